// Round 1
// baseline (7538.259 us; speedup 1.0000x reference)
//
#include <hip/hip_runtime.h>

#define BLOCK 256

// Inclusive-scan num_atoms (B<=~64K) into offsets[B+1] using one block.
__global__ void scan_offsets_kernel(const int* __restrict__ num_atoms, int B,
                                    int* __restrict__ offsets) {
    __shared__ long long partial[1024];
    int t = threadIdx.x;
    int per = (B + 1023) / 1024;
    int base_idx = t * per;
    long long local = 0;
    for (int i = 0; i < per; ++i) {
        int idx = base_idx + i;
        if (idx < B) local += num_atoms[idx];
    }
    partial[t] = local;
    __syncthreads();
    for (int d = 1; d < 1024; d <<= 1) {
        long long v = (t >= d) ? partial[t - d] : 0;
        __syncthreads();
        partial[t] += v;
        __syncthreads();
    }
    long long run = (t == 0) ? 0 : partial[t - 1];
    for (int i = 0; i < per; ++i) {
        int idx = base_idx + i;
        if (idx < B) {
            offsets[idx] = (int)run;
            run += num_atoms[idx];
        }
    }
    if (t == 1023) offsets[B] = (int)partial[1023];
}

__device__ __forceinline__ int find_batch(const int* __restrict__ offsets, int B, int n) {
    int lo = 0, hi = B;  // invariant: offsets[lo] <= n < offsets[hi]
    while (hi - lo > 1) {
        int mid = (lo + hi) >> 1;
        if (offsets[mid] <= n) lo = mid; else hi = mid;
    }
    return lo;
}

// scaled[n] = inv_lat[b]^T @ forces[n]; also zero acc[n].
__global__ void scale_kernel(const float* __restrict__ inv_lat,
                             const float* __restrict__ forces,
                             const int* __restrict__ offsets, int B, int N,
                             float* __restrict__ scaled, float* __restrict__ acc) {
    int n = blockIdx.x * blockDim.x + threadIdx.x;
    if (n >= N) return;
    int b = find_batch(offsets, B, n);
    const float* M = inv_lat + (size_t)b * 9;
    float f0 = forces[n * 3 + 0], f1 = forces[n * 3 + 1], f2 = forces[n * 3 + 2];
    // einsum 'nji,nj->ni': out_i = sum_j M[j][i] * f_j  (M^T @ f)
    float s0 = M[0] * f0 + M[3] * f1 + M[6] * f2;
    float s1 = M[1] * f0 + M[4] * f1 + M[7] * f2;
    float s2 = M[2] * f0 + M[5] * f1 + M[8] * f2;
    scaled[n * 3 + 0] = s0; scaled[n * 3 + 1] = s1; scaled[n * 3 + 2] = s2;
    acc[n * 3 + 0] = 0.f; acc[n * 3 + 1] = 0.f; acc[n * 3 + 2] = 0.f;
}

// One thread per (n,o) pair, t = n*O + o (coalesced symm_map read).
// acc[symm_map[n,o]] += rot[o] @ scaled[n]   (3 fp32 atomics)
__global__ void scatter_kernel(const float* __restrict__ scaled,
                               const float* __restrict__ general_ops,
                               const int* __restrict__ symm_map,
                               float* __restrict__ acc,
                               int total, int O) {
    __shared__ float rot_s[64 * 9];
    for (int i = threadIdx.x; i < O * 9; i += blockDim.x) {
        int o = i / 9, r = i - o * 9;
        rot_s[i] = general_ops[o * 16 + (r / 3) * 4 + (r % 3)];
    }
    __syncthreads();
    int t = blockIdx.x * blockDim.x + threadIdx.x;
    if (t >= total) return;
    unsigned ut = (unsigned)t;
    unsigned n = ut / (unsigned)O;
    unsigned o = ut - n * (unsigned)O;
    float s0 = scaled[n * 3 + 0], s1 = scaled[n * 3 + 1], s2 = scaled[n * 3 + 2];
    const float* R = rot_s + o * 9;
    // einsum 'oij,nj->oni': v_i = sum_j R[i][j] * s_j  (R @ s)
    float v0 = R[0] * s0 + R[1] * s1 + R[2] * s2;
    float v1 = R[3] * s0 + R[4] * s1 + R[5] * s2;
    float v2 = R[6] * s0 + R[7] * s1 + R[8] * s2;
    int tgt = symm_map[t];
    atomicAdd(&acc[(size_t)tgt * 3 + 0], v0);
    atomicAdd(&acc[(size_t)tgt * 3 + 1], v1);
    atomicAdd(&acc[(size_t)tgt * 3 + 2], v2);
}

// out[n] = lat[b]^T @ (acc[n] / num_general_ops[b])
__global__ void output_kernel(const float* __restrict__ lat,
                              const int* __restrict__ num_general_ops,
                              const int* __restrict__ offsets, int B, int N,
                              const float* __restrict__ acc,
                              float* __restrict__ out) {
    int n = blockIdx.x * blockDim.x + threadIdx.x;
    if (n >= N) return;
    int b = find_batch(offsets, B, n);
    float inv_cnt = 1.0f / (float)num_general_ops[b];
    float a0 = acc[n * 3 + 0] * inv_cnt;
    float a1 = acc[n * 3 + 1] * inv_cnt;
    float a2 = acc[n * 3 + 2] * inv_cnt;
    const float* M = lat + (size_t)b * 9;
    out[n * 3 + 0] = M[0] * a0 + M[3] * a1 + M[6] * a2;
    out[n * 3 + 1] = M[1] * a0 + M[4] * a1 + M[7] * a2;
    out[n * 3 + 2] = M[2] * a0 + M[5] * a1 + M[8] * a2;
}

extern "C" void kernel_launch(void* const* d_in, const int* in_sizes, int n_in,
                              void* d_out, int out_size, void* d_ws, size_t ws_size,
                              hipStream_t stream) {
    const float* lattices        = (const float*)d_in[0];
    const float* inv_lattices    = (const float*)d_in[1];
    const float* forces          = (const float*)d_in[2];
    const int*   num_atoms       = (const int*)d_in[3];
    const float* general_ops     = (const float*)d_in[4];
    const int*   symm_map        = (const int*)d_in[5];
    const int*   num_general_ops = (const int*)d_in[6];

    int B = in_sizes[0] / 9;    // lattices (B,3,3)
    int N = in_sizes[2] / 3;    // forces (N,3)
    int O = in_sizes[4] / 16;   // general_ops (O,4,4)

    // Workspace layout: acc (N*3 floats) | offsets (B+1 ints)
    float* acc = (float*)d_ws;
    int* offsets = (int*)((char*)d_ws + (size_t)N * 3 * sizeof(float));
    // Reuse d_out as scratch for `scaled` (fully overwritten by output_kernel).
    float* scaled = (float*)d_out;
    float* out = (float*)d_out;

    scan_offsets_kernel<<<1, 1024, 0, stream>>>(num_atoms, B, offsets);

    int gridN = (N + BLOCK - 1) / BLOCK;
    scale_kernel<<<gridN, BLOCK, 0, stream>>>(inv_lattices, forces, offsets, B, N, scaled, acc);

    long long total_ll = (long long)N * O;
    int total = (int)total_ll;
    int gridS = (int)((total_ll + BLOCK - 1) / BLOCK);
    scatter_kernel<<<gridS, BLOCK, 0, stream>>>(scaled, general_ops, symm_map, acc, total, O);

    output_kernel<<<gridN, BLOCK, 0, stream>>>(lattices, num_general_ops, offsets, B, N, acc, out);
}

// Round 2
// 1832.812 us; speedup vs baseline: 4.1129x; 4.1129x over previous
//
#include <hip/hip_runtime.h>

#define BLOCK 256
#define NB 1024        // number of target buckets
#define GP 512         // grid for hist/place kernels (must be 2*BLOCK for scan_cols)

// ---------------- offsets scan (tiny) ----------------
__global__ void scan_offsets_kernel(const int* __restrict__ num_atoms, int B,
                                    int* __restrict__ offsets) {
    __shared__ long long partial[1024];
    int t = threadIdx.x;
    int per = (B + 1023) / 1024;
    int base_idx = t * per;
    long long local = 0;
    for (int i = 0; i < per; ++i) {
        int idx = base_idx + i;
        if (idx < B) local += num_atoms[idx];
    }
    partial[t] = local;
    __syncthreads();
    for (int d = 1; d < 1024; d <<= 1) {
        long long v = (t >= d) ? partial[t - d] : 0;
        __syncthreads();
        partial[t] += v;
        __syncthreads();
    }
    long long run = (t == 0) ? 0 : partial[t - 1];
    for (int i = 0; i < per; ++i) {
        int idx = base_idx + i;
        if (idx < B) {
            offsets[idx] = (int)run;
            run += num_atoms[idx];
        }
    }
    if (t == 1023) offsets[B] = (int)partial[1023];
}

__device__ __forceinline__ int find_batch(const int* __restrict__ offsets, int B, int n) {
    int lo = 0, hi = B;
    while (hi - lo > 1) {
        int mid = (lo + hi) >> 1;
        if (offsets[mid] <= n) lo = mid; else hi = mid;
    }
    return lo;
}

// ---------------- scaled = inv_lat^T f ; zero acc ----------------
__global__ void scale_kernel(const float* __restrict__ inv_lat,
                             const float* __restrict__ forces,
                             const int* __restrict__ offsets, int B, int N,
                             float* __restrict__ scaled, float* __restrict__ acc) {
    int n = blockIdx.x * blockDim.x + threadIdx.x;
    if (n >= N) return;
    int b = find_batch(offsets, B, n);
    const float* M = inv_lat + (size_t)b * 9;
    float f0 = forces[n * 3 + 0], f1 = forces[n * 3 + 1], f2 = forces[n * 3 + 2];
    float s0 = M[0] * f0 + M[3] * f1 + M[6] * f2;
    float s1 = M[1] * f0 + M[4] * f1 + M[7] * f2;
    float s2 = M[2] * f0 + M[5] * f1 + M[8] * f2;
    scaled[n * 3 + 0] = s0; scaled[n * 3 + 1] = s1; scaled[n * 3 + 2] = s2;
    acc[n * 3 + 0] = 0.f; acc[n * 3 + 1] = 0.f; acc[n * 3 + 2] = 0.f;
}

__device__ __forceinline__ int bucket_of(int tgt, int N) {
    return (int)(((unsigned long long)(unsigned)tgt * (unsigned)NB) / (unsigned)N);
}

// ---------------- pass 1: per-block bucket histogram ----------------
__global__ void hist_kernel(const int* __restrict__ symm_map,
                            long long chunk_base, int chunk_pairs, int N,
                            int* __restrict__ hist) {
    __shared__ int h[NB];
    int tid = threadIdx.x;
    for (int i = tid; i < NB; i += BLOCK) h[i] = 0;
    __syncthreads();
    int span = (chunk_pairs + gridDim.x - 1) / gridDim.x;
    long long bs = (long long)blockIdx.x * span;
    int cnt = chunk_pairs - (int)bs;
    if (cnt > span) cnt = span;
    if (cnt > 0) {
        const int* p = symm_map + chunk_base + bs;
        int base = 0;
        for (; base + 4 * BLOCK <= cnt; base += 4 * BLOCK) {
            int t0 = p[base + tid];
            int t1 = p[base + tid + BLOCK];
            int t2 = p[base + tid + 2 * BLOCK];
            int t3 = p[base + tid + 3 * BLOCK];
            atomicAdd(&h[bucket_of(t0, N)], 1);
            atomicAdd(&h[bucket_of(t1, N)], 1);
            atomicAdd(&h[bucket_of(t2, N)], 1);
            atomicAdd(&h[bucket_of(t3, N)], 1);
        }
        for (int i = base + tid; i < cnt; i += BLOCK)
            atomicAdd(&h[bucket_of(p[i], N)], 1);
    }
    __syncthreads();
    for (int i = tid; i < NB; i += BLOCK) hist[(size_t)blockIdx.x * NB + i] = h[i];
}

// ---------------- pass 2: per-bucket exclusive scan over blocks ----------------
// grid = NB blocks, BLOCK threads; G (=GP) must equal 2*BLOCK.
__global__ void scan_cols_kernel(const int* __restrict__ hist, int cap,
                                 int* __restrict__ offs, int* __restrict__ cnt) {
    int b = blockIdx.x, tid = threadIdx.x;
    int v0 = hist[(size_t)(2 * tid) * NB + b];
    int v1 = hist[(size_t)(2 * tid + 1) * NB + b];
    __shared__ int s[BLOCK];
    s[tid] = v0 + v1;
    __syncthreads();
    for (int d = 1; d < BLOCK; d <<= 1) {
        int x = (tid >= d) ? s[tid - d] : 0;
        __syncthreads();
        s[tid] += x;
        __syncthreads();
    }
    int excl = (tid == 0) ? 0 : s[tid - 1];
    offs[(size_t)(2 * tid) * NB + b]     = b * cap + excl;
    offs[(size_t)(2 * tid + 1) * NB + b] = b * cap + excl + v0;
    if (tid == BLOCK - 1) cnt[b] = (s[BLOCK - 1] < cap) ? s[BLOCK - 1] : cap;
}

// ---------------- pass 3: place records (tgt, v) grouped by bucket ----------------
__global__ void place_kernel(const int* __restrict__ symm_map,
                             const float* __restrict__ scaled,
                             const float* __restrict__ general_ops,
                             const int* __restrict__ offs,
                             long long chunk_base, int chunk_pairs, int N, int O, int cap,
                             float4* __restrict__ records, float* __restrict__ acc) {
    __shared__ int cur[NB];
    __shared__ float R[64 * 9];
    int tid = threadIdx.x;
    for (int i = tid; i < O * 9; i += BLOCK) {
        int o = i / 9, r = i - o * 9;
        R[i] = general_ops[o * 16 + (r / 3) * 4 + (r % 3)];
    }
    for (int i = tid; i < NB; i += BLOCK) cur[i] = offs[(size_t)blockIdx.x * NB + i];
    __syncthreads();
    int span = (chunk_pairs + gridDim.x - 1) / gridDim.x;
    long long bs = (long long)blockIdx.x * span;
    int cnt = chunk_pairs - (int)bs;
    if (cnt > span) cnt = span;
    if (cnt <= 0) return;
    const int* p = symm_map + chunk_base + bs;
    unsigned tbase = (unsigned)(chunk_base + bs);
    for (int i = tid; i < cnt; i += BLOCK) {
        int tgt = p[i];
        unsigned t = tbase + (unsigned)i;
        unsigned n = t / (unsigned)O;
        unsigned o = t - n * (unsigned)O;
        float s0 = scaled[n * 3 + 0], s1 = scaled[n * 3 + 1], s2 = scaled[n * 3 + 2];
        const float* Ro = R + o * 9;
        float v0 = Ro[0] * s0 + Ro[1] * s1 + Ro[2] * s2;
        float v1 = Ro[3] * s0 + Ro[4] * s1 + Ro[5] * s2;
        float v2 = Ro[6] * s0 + Ro[7] * s1 + Ro[8] * s2;
        int b = bucket_of(tgt, N);
        int pos = atomicAdd(&cur[b], 1);
        if (pos - b * cap < cap) {
            records[pos] = make_float4(v0, v1, v2, __int_as_float(tgt));
        } else {  // overflow safety net (empty for uniform data)
            atomicAdd(&acc[(size_t)tgt * 3 + 0], v0);
            atomicAdd(&acc[(size_t)tgt * 3 + 1], v1);
            atomicAdd(&acc[(size_t)tgt * 3 + 2], v2);
        }
    }
}

// ---------------- pass 4: per-bucket LDS accumulation ----------------
__global__ void accum_kernel(const float4* __restrict__ records,
                             const int* __restrict__ cnt, int N, int cap,
                             float* __restrict__ acc) {
    __shared__ float accL[1024 * 3];
    int b = blockIdx.x, tid = threadIdx.x;
    int lo = (int)(((long long)b * N + NB - 1) / NB);
    int hi = (int)(((long long)(b + 1) * N + NB - 1) / NB);
    if (hi > N) hi = N;
    int span3 = (hi - lo) * 3;
    for (int i = tid; i < span3; i += BLOCK) accL[i] = 0.f;
    __syncthreads();
    int c = cnt[b];
    const float4* r = records + (size_t)b * cap;
    for (int i = tid; i < c; i += BLOCK) {
        float4 f = r[i];
        int tgt = __float_as_int(f.w);
        int local = tgt - lo;
        atomicAdd(&accL[local * 3 + 0], f.x);
        atomicAdd(&accL[local * 3 + 1], f.y);
        atomicAdd(&accL[local * 3 + 2], f.z);
    }
    __syncthreads();
    float* g = acc + (size_t)lo * 3;
    for (int i = tid; i < span3; i += BLOCK) g[i] += accL[i];
}

// ---------------- fallback scatter (device atomics) ----------------
__global__ void scatter_kernel(const float* __restrict__ scaled,
                               const float* __restrict__ general_ops,
                               const int* __restrict__ symm_map,
                               float* __restrict__ acc,
                               int total, int O) {
    __shared__ float rot_s[64 * 9];
    for (int i = threadIdx.x; i < O * 9; i += blockDim.x) {
        int o = i / 9, r = i - o * 9;
        rot_s[i] = general_ops[o * 16 + (r / 3) * 4 + (r % 3)];
    }
    __syncthreads();
    int t = blockIdx.x * blockDim.x + threadIdx.x;
    if (t >= total) return;
    unsigned ut = (unsigned)t;
    unsigned n = ut / (unsigned)O;
    unsigned o = ut - n * (unsigned)O;
    float s0 = scaled[n * 3 + 0], s1 = scaled[n * 3 + 1], s2 = scaled[n * 3 + 2];
    const float* R = rot_s + o * 9;
    float v0 = R[0] * s0 + R[1] * s1 + R[2] * s2;
    float v1 = R[3] * s0 + R[4] * s1 + R[5] * s2;
    float v2 = R[6] * s0 + R[7] * s1 + R[8] * s2;
    int tgt = symm_map[t];
    atomicAdd(&acc[(size_t)tgt * 3 + 0], v0);
    atomicAdd(&acc[(size_t)tgt * 3 + 1], v1);
    atomicAdd(&acc[(size_t)tgt * 3 + 2], v2);
}

// ---------------- out = lat^T (acc / count) ----------------
__global__ void output_kernel(const float* __restrict__ lat,
                              const int* __restrict__ num_general_ops,
                              const int* __restrict__ offsets, int B, int N,
                              const float* __restrict__ acc,
                              float* __restrict__ out) {
    int n = blockIdx.x * blockDim.x + threadIdx.x;
    if (n >= N) return;
    int b = find_batch(offsets, B, n);
    float inv_cnt = 1.0f / (float)num_general_ops[b];
    float a0 = acc[n * 3 + 0] * inv_cnt;
    float a1 = acc[n * 3 + 1] * inv_cnt;
    float a2 = acc[n * 3 + 2] * inv_cnt;
    const float* M = lat + (size_t)b * 9;
    out[n * 3 + 0] = M[0] * a0 + M[3] * a1 + M[6] * a2;
    out[n * 3 + 1] = M[1] * a0 + M[4] * a1 + M[7] * a2;
    out[n * 3 + 2] = M[2] * a0 + M[5] * a1 + M[8] * a2;
}

static inline size_t align16(size_t x) { return (x + 15) & ~(size_t)15; }

extern "C" void kernel_launch(void* const* d_in, const int* in_sizes, int n_in,
                              void* d_out, int out_size, void* d_ws, size_t ws_size,
                              hipStream_t stream) {
    const float* lattices        = (const float*)d_in[0];
    const float* inv_lattices    = (const float*)d_in[1];
    const float* forces          = (const float*)d_in[2];
    const int*   num_atoms       = (const int*)d_in[3];
    const float* general_ops     = (const float*)d_in[4];
    const int*   symm_map        = (const int*)d_in[5];
    const int*   num_general_ops = (const int*)d_in[6];

    int B = in_sizes[0] / 9;
    int N = in_sizes[2] / 3;
    int O = in_sizes[4] / 16;
    long long total = (long long)N * O;

    // ---- workspace layout ----
    char* p = (char*)d_ws;
    size_t used = 0;
    float* scaled = (float*)(p + used); used = align16(used + (size_t)N * 3 * sizeof(float));
    float* acc    = (float*)(p + used); used = align16(used + (size_t)N * 3 * sizeof(float));
    int* offsets  = (int*)(p + used);   used = align16(used + (size_t)(B + 1) * sizeof(int));
    int* hist     = (int*)(p + used);   used = align16(used + (size_t)GP * NB * sizeof(int));
    int* offs     = (int*)(p + used);   used = align16(used + (size_t)GP * NB * sizeof(int));
    int* cnt      = (int*)(p + used);   used = align16(used + (size_t)NB * sizeof(int));
    size_t remaining = (ws_size > used) ? ws_size - used : 0;

    // choose chunk count C so records fit; cap = mean + 25% + 512 slack
    int C = -1, cap = 0;
    for (int c = 1; c <= 64; ++c) {
        long long cp = (total + c - 1) / c;
        long long mean = (cp + NB - 1) / NB;
        long long capc = mean + mean / 4 + 512;
        if ((size_t)NB * capc * sizeof(float4) <= remaining) { C = c; cap = (int)capc; break; }
    }
    bool fast = (C > 0) && (N <= NB * 1024) && (O <= 64) && (total < (1LL << 31));

    int gridN = (N + BLOCK - 1) / BLOCK;
    scan_offsets_kernel<<<1, 1024, 0, stream>>>(num_atoms, B, offsets);

    if (fast) {
        float4* records = (float4*)(p + used);
        scale_kernel<<<gridN, BLOCK, 0, stream>>>(inv_lattices, forces, offsets, B, N, scaled, acc);
        long long chunk_pairs_nom = (total + C - 1) / C;
        for (int c = 0; c < C; ++c) {
            long long base = (long long)c * chunk_pairs_nom;
            int cp = (int)(((total - base) < chunk_pairs_nom) ? (total - base) : chunk_pairs_nom);
            if (cp <= 0) break;
            hist_kernel<<<GP, BLOCK, 0, stream>>>(symm_map, base, cp, N, hist);
            scan_cols_kernel<<<NB, BLOCK, 0, stream>>>(hist, cap, offs, cnt);
            place_kernel<<<GP, BLOCK, 0, stream>>>(symm_map, scaled, general_ops, offs,
                                                   base, cp, N, O, cap, records, acc);
            accum_kernel<<<NB, BLOCK, 0, stream>>>(records, cnt, N, cap, acc);
        }
        output_kernel<<<gridN, BLOCK, 0, stream>>>(lattices, num_general_ops, offsets, B, N, acc, out_size ? (float*)d_out : (float*)d_out);
    } else {
        // fallback: device-atomic scatter (uses d_out as scaled scratch)
        float* scaled_f = (float*)d_out;
        scale_kernel<<<gridN, BLOCK, 0, stream>>>(inv_lattices, forces, offsets, B, N, scaled_f, acc);
        int gridS = (int)((total + BLOCK - 1) / BLOCK);
        scatter_kernel<<<gridS, BLOCK, 0, stream>>>(scaled_f, general_ops, symm_map, acc, (int)total, O);
        output_kernel<<<gridN, BLOCK, 0, stream>>>(lattices, num_general_ops, offsets, B, N, acc, (float*)d_out);
    }
}